// Round 1
// baseline (1027.028 us; speedup 1.0000x reference)
//
#include <hip/hip_runtime.h>
#include <cstdint>

// GCN: 2x (gemm -> gather-aggregate -> bias+relu) + linear head + log_softmax.
// Strategy: fold dinv[row] into GEMM epilogue so aggregation is a pure
// gather-sum over a per-call-built CSR (by dst). No float atomics anywhere.

__global__ void k_count(const int* __restrict__ dst, int* __restrict__ cnt, int E) {
    int e = blockIdx.x * blockDim.x + threadIdx.x;
    if (e < E) atomicAdd(&cnt[dst[e]], 1);
}

__global__ void k_dinv(const int* __restrict__ cnt, float* __restrict__ dinv, int n) {
    int i = blockIdx.x * blockDim.x + threadIdx.x;
    if (i < n) dinv[i] = rsqrtf((float)cnt[i] + 1.0f);  // +1 self-loop; deg>=1 always
}

// ---- 3-kernel exclusive scan of cnt[] -> rofs[] (N=100000, 391 blocks) ----
__global__ void k_scanA(const int* __restrict__ cnt, int* __restrict__ rofs,
                        int* __restrict__ blks, int n) {
    __shared__ int sh[256];
    int t = threadIdx.x, i = blockIdx.x * 256 + t;
    int v = (i < n) ? cnt[i] : 0;
    sh[t] = v; __syncthreads();
    #pragma unroll
    for (int o = 1; o < 256; o <<= 1) {
        int x = (t >= o) ? sh[t - o] : 0;
        __syncthreads(); sh[t] += x; __syncthreads();
    }
    if (i < n) rofs[i] = sh[t] - v;          // exclusive within block
    if (t == 255) blks[blockIdx.x] = sh[255]; // block total
}

__global__ void k_scanB(int* __restrict__ blks, int nb) {
    __shared__ int sh[512];
    int t = threadIdx.x;
    int v = (t < nb) ? blks[t] : 0;
    sh[t] = v; __syncthreads();
    #pragma unroll
    for (int o = 1; o < 512; o <<= 1) {
        int x = (t >= o) ? sh[t - o] : 0;
        __syncthreads(); sh[t] += x; __syncthreads();
    }
    if (t < nb) blks[t] = sh[t] - v;         // exclusive block offsets
}

__global__ void k_scanC(int* __restrict__ rofs, int* __restrict__ fill,
                        const int* __restrict__ blks, int n, int E) {
    int i = blockIdx.x * 256 + threadIdx.x;
    if (i < n) { int r = rofs[i] + blks[blockIdx.x]; rofs[i] = r; fill[i] = r; }
    if (i == 0) rofs[n] = E;
}

__global__ void k_fill(const int* __restrict__ src, const int* __restrict__ dst,
                       int* __restrict__ fill, int* __restrict__ csrc, int E) {
    int e = blockIdx.x * blockDim.x + threadIdx.x;
    if (e < E) { int pos = atomicAdd(&fill[dst[e]], 1); csrc[pos] = src[e]; }
}

// ---- GEMM: G[row,:] = (X[row,:] @ W) * dinv[row].  HID=64 cols fixed. ----
// Quarter-wave (16 lanes) per row; lane p computes cols [4p,4p+4).
// W resident in LDS; x row held in registers, broadcast via width-16 shuffles.
template<int K>
__global__ __launch_bounds__(256) void k_gemm(const float* __restrict__ X,
        const float* __restrict__ Wm, const float* __restrict__ dinv,
        float* __restrict__ G, int nrows) {
    __shared__ float wl[K * 64];          // K=256 -> 64KB, K=64 -> 16KB
    int t = threadIdx.x;
    for (int i = t; i < K * 16; i += 256)
        ((float4*)wl)[i] = ((const float4*)Wm)[i];
    __syncthreads();
    const int p = t & 15;                  // lane-in-quarter
    const int qid = t >> 4;                // 0..15 = row within 16-row group
    constexpr int PER = K / 16;            // x floats per lane
    constexpr int NV = K / 64;             // float4s per lane
    for (int row = blockIdx.x * 16 + qid; row < nrows; row += gridDim.x * 16) {
        const float4* xr = (const float4*)(X + (size_t)row * K);
        float4 xq[NV];
        #pragma unroll
        for (int m = 0; m < NV; ++m) xq[m] = xr[p * NV + m];
        float4 acc = make_float4(0.f, 0.f, 0.f, 0.f);
        #pragma unroll
        for (int k = 0; k < K; ++k) {
            const int srcl = k / PER, rem = k % PER, m = rem >> 2, c = rem & 3;
            float xv = (c == 0) ? xq[m].x : (c == 1) ? xq[m].y : (c == 2) ? xq[m].z : xq[m].w;
            float xk = __shfl(xv, srcl, 16);
            const float4 wv = *(((const float4*)(wl + k * 64)) + p);
            acc.x += xk * wv.x; acc.y += xk * wv.y;
            acc.z += xk * wv.z; acc.w += xk * wv.w;
        }
        const float dv = dinv[row];
        acc.x *= dv; acc.y *= dv; acc.z *= dv; acc.w *= dv;
        *(((float4*)(G + (size_t)row * 64)) + p) = acc;
    }
}

// ---- Aggregate: H[d,:] = relu(dinv[d]*(G[d,:] + sum_{e in CSR[d]} G[src_e,:]) + b)
// One wave per node; lane = feature dim. Edges prefetched 64-wide (coalesced),
// broadcast via shuffle; gather read of G row is one coalesced 256B load.
__global__ __launch_bounds__(256) void k_agg(const float* __restrict__ G,
        const int* __restrict__ rofs, const int* __restrict__ csrc,
        const float* __restrict__ dinv, const float* __restrict__ bias,
        float* __restrict__ H, int nrows) {
    int l = threadIdx.x & 63;
    int d = blockIdx.x * 4 + (threadIdx.x >> 6);
    if (d >= nrows) return;
    int beg = rofs[d], end = rofs[d + 1];
    float acc = G[(size_t)d * 64 + l];     // self-loop term (already dinv-scaled)
    for (int e = beg; e < end; e += 64) {
        int nrem = end - e;
        int idx = (l < nrem) ? csrc[e + l] : 0;
        int cnt = nrem < 64 ? nrem : 64;
        int kk = 0;
        for (; kk + 4 <= cnt; kk += 4) {
            int s0 = __shfl(idx, kk),     s1 = __shfl(idx, kk + 1);
            int s2 = __shfl(idx, kk + 2), s3 = __shfl(idx, kk + 3);
            float v0 = G[(size_t)s0 * 64 + l], v1 = G[(size_t)s1 * 64 + l];
            float v2 = G[(size_t)s2 * 64 + l], v3 = G[(size_t)s3 * 64 + l];
            acc += v0; acc += v1; acc += v2; acc += v3;
        }
        for (; kk < cnt; ++kk) {
            int s = __shfl(idx, kk);
            acc += G[(size_t)s * 64 + l];
        }
    }
    float o = acc * dinv[d] + bias[l];
    H[(size_t)d * 64 + l] = fmaxf(o, 0.0f);
}

// ---- Head: out[row,:] = log_softmax(H[row,:] @ W3 + b3), OUT=40 ----
__global__ __launch_bounds__(256) void k_final(const float* __restrict__ H,
        const float* __restrict__ W3, const float* __restrict__ b3,
        float* __restrict__ out, int nrows) {
    __shared__ float wl[64 * 40];
    __shared__ float bl[40];
    int t = threadIdx.x;
    for (int i = t; i < 640; i += 256)
        ((float4*)wl)[i] = ((const float4*)W3)[i];
    if (t < 40) bl[t] = b3[t];
    __syncthreads();
    for (int row = blockIdx.x * 256 + t; row < nrows; row += gridDim.x * 256) {
        float acc[40];
        #pragma unroll
        for (int j = 0; j < 40; ++j) acc[j] = bl[j];
        const float4* hr = (const float4*)(H + (size_t)row * 64);
        #pragma unroll
        for (int k4 = 0; k4 < 16; ++k4) {
            float4 h4 = hr[k4];
            float hv[4] = {h4.x, h4.y, h4.z, h4.w};
            #pragma unroll
            for (int c = 0; c < 4; ++c) {
                const float4* wr = (const float4*)(wl + (k4 * 4 + c) * 40);
                #pragma unroll
                for (int j4 = 0; j4 < 10; ++j4) {
                    float4 wv = wr[j4];
                    acc[j4 * 4 + 0] += hv[c] * wv.x;
                    acc[j4 * 4 + 1] += hv[c] * wv.y;
                    acc[j4 * 4 + 2] += hv[c] * wv.z;
                    acc[j4 * 4 + 3] += hv[c] * wv.w;
                }
            }
        }
        float m = acc[0];
        #pragma unroll
        for (int j = 1; j < 40; ++j) m = fmaxf(m, acc[j]);
        float s = 0.f;
        #pragma unroll
        for (int j = 0; j < 40; ++j) s += expf(acc[j] - m);
        float lse = m + logf(s);
        float* orow = out + (size_t)row * 40;
        #pragma unroll
        for (int j4 = 0; j4 < 10; ++j4) {
            ((float4*)orow)[j4] = make_float4(acc[j4 * 4 + 0] - lse, acc[j4 * 4 + 1] - lse,
                                              acc[j4 * 4 + 2] - lse, acc[j4 * 4 + 3] - lse);
        }
    }
}

extern "C" void kernel_launch(void* const* d_in, const int* in_sizes, int n_in,
                              void* d_out, int out_size, void* d_ws, size_t ws_size,
                              hipStream_t stream) {
    const float* x  = (const float*)d_in[0];
    const int*   ei = (const int*)d_in[1];     // [2][E]: row0=src, row1=dst
    const float* W1 = (const float*)d_in[2];
    const float* b1 = (const float*)d_in[3];
    const float* W2 = (const float*)d_in[4];
    const float* b2 = (const float*)d_in[5];
    const float* W3 = (const float*)d_in[6];
    const float* b3 = (const float*)d_in[7];
    float* out = (float*)d_out;

    const int HID = in_sizes[3];            // 64
    const int IND = in_sizes[2] / HID;      // 256
    const int N   = in_sizes[0] / IND;      // 100000
    const int E   = in_sizes[1] / 2;        // 3200000
    (void)HID; (void)n_in; (void)out_size; (void)ws_size;

    // workspace carve-up (~66 MB)
    char* ws = (char*)d_ws;
    size_t off = 0;
    auto alloc = [&](size_t bytes) -> char* {
        char* p = ws + off;
        off = (off + bytes + 255) & ~(size_t)255;
        return p;
    };
    int*   cnt  = (int*)  alloc((size_t)N * 4);
    int*   rofs = (int*)  alloc(((size_t)N + 1) * 4);
    int*   fill = (int*)  alloc((size_t)N * 4);
    float* dinv = (float*)alloc((size_t)N * 4);
    int*   blks = (int*)  alloc(4096);
    int*   csrc = (int*)  alloc((size_t)E * 4);
    float* g    = (float*)alloc((size_t)N * 64 * 4);
    float* h    = (float*)alloc((size_t)N * 64 * 4);

    const int* esrc = ei;
    const int* edst = ei + E;

    const int gE = (E + 255) / 256;
    const int gN = (N + 255) / 256;

    hipMemsetAsync(cnt, 0, (size_t)N * 4, stream);
    k_count<<<gE, 256, 0, stream>>>(edst, cnt, E);
    k_dinv <<<gN, 256, 0, stream>>>(cnt, dinv, N);
    k_scanA<<<gN, 256, 0, stream>>>(cnt, rofs, blks, N);
    k_scanB<<<1, 512, 0, stream>>>(blks, gN);
    k_scanC<<<gN, 256, 0, stream>>>(rofs, fill, blks, N, E);
    k_fill <<<gE, 256, 0, stream>>>(esrc, edst, fill, csrc, E);

    k_gemm<256><<<1024, 256, 0, stream>>>(x, W1, dinv, g, N);
    k_agg      <<<(N + 3) / 4, 256, 0, stream>>>(g, rofs, csrc, dinv, b1, h, N);
    k_gemm<64> <<<1024, 256, 0, stream>>>(h, W2, dinv, g, N);
    k_agg      <<<(N + 3) / 4, 256, 0, stream>>>(g, rofs, csrc, dinv, b2, h, N);
    k_final    <<<gN, 256, 0, stream>>>(h, W3, b3, out, N);
}

// Round 2
// 759.777 us; speedup vs baseline: 1.3518x; 1.3518x over previous
//
#include <hip/hip_runtime.h>
#include <cstdint>

// GCN: 2x (gemm -> gather-aggregate -> bias+relu) + linear head + log_softmax.
// dinv[row] folded into GEMM epilogue; aggregation = pure gather-sum over a
// per-call-built CSR (by dst). No float atomics anywhere.

__global__ void k_count(const int* __restrict__ dst, int* __restrict__ cnt, int E) {
    int e = blockIdx.x * blockDim.x + threadIdx.x;
    if (e < E) atomicAdd(&cnt[dst[e]], 1);
}

__global__ void k_dinv(const int* __restrict__ cnt, float* __restrict__ dinv, int n) {
    int i = blockIdx.x * blockDim.x + threadIdx.x;
    if (i < n) dinv[i] = rsqrtf((float)cnt[i] + 1.0f);  // +1 self-loop; deg>=1 always
}

// ---- 3-kernel exclusive scan of cnt[] -> rofs[] (N=100000, 391 blocks) ----
__global__ void k_scanA(const int* __restrict__ cnt, int* __restrict__ rofs,
                        int* __restrict__ blks, int n) {
    __shared__ int sh[256];
    int t = threadIdx.x, i = blockIdx.x * 256 + t;
    int v = (i < n) ? cnt[i] : 0;
    sh[t] = v; __syncthreads();
    #pragma unroll
    for (int o = 1; o < 256; o <<= 1) {
        int x = (t >= o) ? sh[t - o] : 0;
        __syncthreads(); sh[t] += x; __syncthreads();
    }
    if (i < n) rofs[i] = sh[t] - v;
    if (t == 255) blks[blockIdx.x] = sh[255];
}

__global__ void k_scanB(int* __restrict__ blks, int nb) {
    __shared__ int sh[512];
    int t = threadIdx.x;
    int v = (t < nb) ? blks[t] : 0;
    sh[t] = v; __syncthreads();
    #pragma unroll
    for (int o = 1; o < 512; o <<= 1) {
        int x = (t >= o) ? sh[t - o] : 0;
        __syncthreads(); sh[t] += x; __syncthreads();
    }
    if (t < nb) blks[t] = sh[t] - v;
}

__global__ void k_scanC(int* __restrict__ rofs, int* __restrict__ fill,
                        const int* __restrict__ blks, int n, int E) {
    int i = blockIdx.x * 256 + threadIdx.x;
    if (i < n) { int r = rofs[i] + blks[blockIdx.x]; rofs[i] = r; fill[i] = r; }
    if (i == 0) rofs[n] = E;
}

__global__ void k_fill(const int* __restrict__ src, const int* __restrict__ dst,
                       int* __restrict__ fill, int* __restrict__ csrc, int E) {
    int e = blockIdx.x * blockDim.x + threadIdx.x;
    if (e < E) { int pos = atomicAdd(&fill[dst[e]], 1); csrc[pos] = src[e]; }
}

// ---- GEMM: G[row,:] = (X[row,:] @ W) * dinv[row].  64 output cols fixed. ----
// Block tile: 128 rows x 64 cols, BK=32. X staged TRANSPOSED in LDS
// (Xs[k][row], pitch 132 -> conflict-free b128 compute reads over 4 rows).
// Thread tile: 4 rows x 8 cols (acc[4][8]); per k: 3x ds_read_b128 + 32 FMA.
template<int K>
__global__ __launch_bounds__(256) void k_gemm(const float* __restrict__ X,
        const float* __restrict__ Wm, const float* __restrict__ dinv,
        float* __restrict__ G, int nrows) {
    constexpr int BK = 32;
    constexpr int NCH = K / BK;
    constexpr int PITCH = 132;             // 128 rows + 4 pad (16B-aligned rows)
    __shared__ float Xs[BK * PITCH];       // 16.5 KB
    __shared__ float Ws[BK * 64];          // 8 KB
    const int t = threadIdx.x;
    const int cg = t & 7;                  // col group: cols cg*8 .. +8
    const int rg = t >> 3;                 // row group: rows rg*4 .. +4
    const int brow = blockIdx.x * 128;

    float acc[4][8];
    #pragma unroll
    for (int r = 0; r < 4; ++r)
        #pragma unroll
        for (int c = 0; c < 8; ++c) acc[r][c] = 0.f;

    for (int ch = 0; ch < NCH; ++ch) {
        if (ch) __syncthreads();
        // stage X chunk: 128 rows x 32 k, transposed into Xs[k][row]
        #pragma unroll
        for (int i = 0; i < 4; ++i) {
            int f = t + i * 256;           // 0..1023
            int r = f >> 3, c4 = f & 7;    // row, k-quad
            int gr = brow + r;
            float4 v = make_float4(0.f, 0.f, 0.f, 0.f);
            if (gr < nrows)
                v = *(const float4*)(X + (size_t)gr * K + ch * BK + c4 * 4);
            Xs[(c4 * 4 + 0) * PITCH + r] = v.x;
            Xs[(c4 * 4 + 1) * PITCH + r] = v.y;
            Xs[(c4 * 4 + 2) * PITCH + r] = v.z;
            Xs[(c4 * 4 + 3) * PITCH + r] = v.w;
        }
        // stage W chunk: 32 k x 64 cols
        #pragma unroll
        for (int i = 0; i < 2; ++i) {
            int f = t + i * 256;           // 0..511
            int k = f >> 4, c4 = f & 15;
            *(float4*)(Ws + k * 64 + c4 * 4) =
                *(const float4*)(Wm + (size_t)(ch * BK + k) * 64 + c4 * 4);
        }
        __syncthreads();

        #pragma unroll
        for (int k = 0; k < BK; ++k) {
            float4 xa = *(const float4*)(Xs + k * PITCH + rg * 4);   // 4 rows
            float4 w0 = *(const float4*)(Ws + k * 64 + cg * 8);
            float4 w1 = *(const float4*)(Ws + k * 64 + cg * 8 + 4);
#define FMA_ROW(r, xv) \
            acc[r][0] += (xv) * w0.x; acc[r][1] += (xv) * w0.y; \
            acc[r][2] += (xv) * w0.z; acc[r][3] += (xv) * w0.w; \
            acc[r][4] += (xv) * w1.x; acc[r][5] += (xv) * w1.y; \
            acc[r][6] += (xv) * w1.z; acc[r][7] += (xv) * w1.w;
            FMA_ROW(0, xa.x) FMA_ROW(1, xa.y) FMA_ROW(2, xa.z) FMA_ROW(3, xa.w)
#undef FMA_ROW
        }
    }
    // epilogue: scale by dinv[row], store
    #pragma unroll
    for (int r = 0; r < 4; ++r) {
        int gr = brow + rg * 4 + r;
        if (gr < nrows) {
            float dv = dinv[gr];
            float4 o0 = make_float4(acc[r][0] * dv, acc[r][1] * dv,
                                    acc[r][2] * dv, acc[r][3] * dv);
            float4 o1 = make_float4(acc[r][4] * dv, acc[r][5] * dv,
                                    acc[r][6] * dv, acc[r][7] * dv);
            *(float4*)(G + (size_t)gr * 64 + cg * 8)     = o0;
            *(float4*)(G + (size_t)gr * 64 + cg * 8 + 4) = o1;
        }
    }
}

// ---- Aggregate: H[d,:] = relu(dinv[d]*(G[d,:] + sum_{e in CSR[d]} G[src_e,:]) + b)
// One wave per node. Quarter-wave (16 lanes x float4 = 256B row) per edge ->
// 4 edges in flight per iteration, unroll 4 -> up to 4 b128 loads outstanding.
// Cross-quarter reduce via shfl_xor(16/32) at the end.
__global__ __launch_bounds__(256) void k_agg(const float* __restrict__ G,
        const int* __restrict__ rofs, const int* __restrict__ csrc,
        const float* __restrict__ dinv, const float* __restrict__ bias,
        float* __restrict__ H, int nrows) {
    const int l = threadIdx.x & 63;
    const int q = l >> 4;                  // quarter 0..3
    const int p = l & 15;                  // float4 slot within row
    const int d = blockIdx.x * 4 + (threadIdx.x >> 6);
    if (d >= nrows) return;                // wave-uniform
    const int beg = rofs[d], end = rofs[d + 1];
    const float4* __restrict__ G4 = (const float4*)G;   // row stride = 16
    float4 acc = make_float4(0.f, 0.f, 0.f, 0.f);

    for (int e = beg; e < end; e += 64) {
        int nrem = end - e; if (nrem > 64) nrem = 64;
        int idx = (l < nrem) ? csrc[e + l] : 0;
        const int full = nrem >> 2;        // complete groups of 4 edges
        int kk = 0;
        for (; kk + 4 <= full; kk += 4) {
            int s0 = __shfl(idx, (kk + 0) * 4 + q);
            int s1 = __shfl(idx, (kk + 1) * 4 + q);
            int s2 = __shfl(idx, (kk + 2) * 4 + q);
            int s3 = __shfl(idx, (kk + 3) * 4 + q);
            float4 v0 = G4[s0 * 16 + p];
            float4 v1 = G4[s1 * 16 + p];
            float4 v2 = G4[s2 * 16 + p];
            float4 v3 = G4[s3 * 16 + p];
            acc.x += v0.x; acc.y += v0.y; acc.z += v0.z; acc.w += v0.w;
            acc.x += v1.x; acc.y += v1.y; acc.z += v1.z; acc.w += v1.w;
            acc.x += v2.x; acc.y += v2.y; acc.z += v2.z; acc.w += v2.w;
            acc.x += v3.x; acc.y += v3.y; acc.z += v3.z; acc.w += v3.w;
        }
        for (; kk < full; ++kk) {
            int s = __shfl(idx, kk * 4 + q);
            float4 v = G4[s * 16 + p];
            acc.x += v.x; acc.y += v.y; acc.z += v.z; acc.w += v.w;
        }
        int tq = full * 4 + q;             // tail edges, one per quarter
        if (tq < nrem) {
            int s = __shfl(idx, tq);
            float4 v = G4[s * 16 + p];
            acc.x += v.x; acc.y += v.y; acc.z += v.z; acc.w += v.w;
        }
    }
    // reduce the 4 quarter-accumulators (all lanes end with the full sum)
    #pragma unroll
    for (int off = 16; off <= 32; off <<= 1) {
        acc.x += __shfl_xor(acc.x, off);
        acc.y += __shfl_xor(acc.y, off);
        acc.z += __shfl_xor(acc.z, off);
        acc.w += __shfl_xor(acc.w, off);
    }
    if (q == 0) {
        float4 self = G4[d * 16 + p];
        float dv = dinv[d];
        float4 b4 = ((const float4*)bias)[p];
        float4 o;
        o.x = fmaxf((acc.x + self.x) * dv + b4.x, 0.f);
        o.y = fmaxf((acc.y + self.y) * dv + b4.y, 0.f);
        o.z = fmaxf((acc.z + self.z) * dv + b4.z, 0.f);
        o.w = fmaxf((acc.w + self.w) * dv + b4.w, 0.f);
        ((float4*)H)[d * 16 + p] = o;
    }
}

// ---- Head: out[row,:] = log_softmax(H[row,:] @ W3 + b3), OUT=40 ----
__global__ __launch_bounds__(256) void k_final(const float* __restrict__ H,
        const float* __restrict__ W3, const float* __restrict__ b3,
        float* __restrict__ out, int nrows) {
    __shared__ float wl[64 * 40];
    __shared__ float bl[40];
    int t = threadIdx.x;
    for (int i = t; i < 640; i += 256)
        ((float4*)wl)[i] = ((const float4*)W3)[i];
    if (t < 40) bl[t] = b3[t];
    __syncthreads();
    for (int row = blockIdx.x * 256 + t; row < nrows; row += gridDim.x * 256) {
        float acc[40];
        #pragma unroll
        for (int j = 0; j < 40; ++j) acc[j] = bl[j];
        const float4* hr = (const float4*)(H + (size_t)row * 64);
        #pragma unroll
        for (int k4 = 0; k4 < 16; ++k4) {
            float4 h4 = hr[k4];
            float hv[4] = {h4.x, h4.y, h4.z, h4.w};
            #pragma unroll
            for (int c = 0; c < 4; ++c) {
                const float4* wr = (const float4*)(wl + (k4 * 4 + c) * 40);
                #pragma unroll
                for (int j4 = 0; j4 < 10; ++j4) {
                    float4 wv = wr[j4];
                    acc[j4 * 4 + 0] += hv[c] * wv.x;
                    acc[j4 * 4 + 1] += hv[c] * wv.y;
                    acc[j4 * 4 + 2] += hv[c] * wv.z;
                    acc[j4 * 4 + 3] += hv[c] * wv.w;
                }
            }
        }
        float m = acc[0];
        #pragma unroll
        for (int j = 1; j < 40; ++j) m = fmaxf(m, acc[j]);
        float s = 0.f;
        #pragma unroll
        for (int j = 0; j < 40; ++j) s += expf(acc[j] - m);
        float lse = m + logf(s);
        float* orow = out + (size_t)row * 40;
        #pragma unroll
        for (int j4 = 0; j4 < 10; ++j4) {
            ((float4*)orow)[j4] = make_float4(acc[j4 * 4 + 0] - lse, acc[j4 * 4 + 1] - lse,
                                              acc[j4 * 4 + 2] - lse, acc[j4 * 4 + 3] - lse);
        }
    }
}

extern "C" void kernel_launch(void* const* d_in, const int* in_sizes, int n_in,
                              void* d_out, int out_size, void* d_ws, size_t ws_size,
                              hipStream_t stream) {
    const float* x  = (const float*)d_in[0];
    const int*   ei = (const int*)d_in[1];     // [2][E]: row0=src, row1=dst
    const float* W1 = (const float*)d_in[2];
    const float* b1 = (const float*)d_in[3];
    const float* W2 = (const float*)d_in[4];
    const float* b2 = (const float*)d_in[5];
    const float* W3 = (const float*)d_in[6];
    const float* b3 = (const float*)d_in[7];
    float* out = (float*)d_out;

    const int HID = in_sizes[3];            // 64
    const int IND = in_sizes[2] / HID;      // 256
    const int N   = in_sizes[0] / IND;      // 100000
    const int E   = in_sizes[1] / 2;        // 3200000
    (void)HID; (void)n_in; (void)out_size; (void)ws_size;

    char* ws = (char*)d_ws;
    size_t off = 0;
    auto alloc = [&](size_t bytes) -> char* {
        char* p = ws + off;
        off = (off + bytes + 255) & ~(size_t)255;
        return p;
    };
    int*   cnt  = (int*)  alloc((size_t)N * 4);
    int*   rofs = (int*)  alloc(((size_t)N + 1) * 4);
    int*   fill = (int*)  alloc((size_t)N * 4);
    float* dinv = (float*)alloc((size_t)N * 4);
    int*   blks = (int*)  alloc(4096);
    int*   csrc = (int*)  alloc((size_t)E * 4);
    float* g    = (float*)alloc((size_t)N * 64 * 4);
    float* h    = (float*)alloc((size_t)N * 64 * 4);

    const int* esrc = ei;
    const int* edst = ei + E;

    const int gE = (E + 255) / 256;
    const int gN = (N + 255) / 256;
    const int gM = (N + 127) / 128;

    hipMemsetAsync(cnt, 0, (size_t)N * 4, stream);
    k_count<<<gE, 256, 0, stream>>>(edst, cnt, E);
    k_dinv <<<gN, 256, 0, stream>>>(cnt, dinv, N);
    k_scanA<<<gN, 256, 0, stream>>>(cnt, rofs, blks, N);
    k_scanB<<<1, 512, 0, stream>>>(blks, gN);
    k_scanC<<<gN, 256, 0, stream>>>(rofs, fill, blks, N, E);
    k_fill <<<gE, 256, 0, stream>>>(esrc, edst, fill, csrc, E);

    k_gemm<256><<<gM, 256, 0, stream>>>(x, W1, dinv, g, N);
    k_agg      <<<(N + 3) / 4, 256, 0, stream>>>(g, rofs, csrc, dinv, b1, h, N);
    k_gemm<64> <<<gM, 256, 0, stream>>>(h, W2, dinv, g, N);
    k_agg      <<<(N + 3) / 4, 256, 0, stream>>>(g, rofs, csrc, dinv, b2, h, N);
    k_final    <<<gN, 256, 0, stream>>>(h, W3, b3, out, N);
}